// Round 8
// baseline (57.898 us; speedup 1.0000x reference)
//
#include <hip/hip_runtime.h>

#define BATCH 32
#define LSEQ 4096
#define HDIM 512
#define PARTS 4

typedef float f32x4 __attribute__((ext_vector_type(4)));

// -----------------------------------------------------------------------------
// Kernel 1: partial projection. grid (BATCH, PARTS), block 512.  (unchanged)
// -----------------------------------------------------------------------------
__global__ __launch_bounds__(512) void proj_kernel(
    const float* __restrict__ hidden, const float* __restrict__ W,
    const float* __restrict__ bias, float* __restrict__ vpart,
    float* __restrict__ cpart)
{
    const int b    = blockIdx.x;
    const int part = blockIdx.y;
    const int h    = threadIdx.x;
    const int OS   = HDIM / PARTS;          // 128
    const int obase = part * OS;

    __shared__ float s_hl[HDIM / PARTS];
    if (h < OS) s_hl[h] = hidden[(BATCH + b) * HDIM + obase + h];
    __syncthreads();

    float acc = 0.f;
#pragma unroll 16
    for (int o = 0; o < OS; ++o) {
        acc += s_hl[o] * W[(obase + o) * HDIM + h];
    }
    vpart[(part * BATCH + b) * HDIM + h] = acc;

    float p = (h < OS) ? s_hl[h] * bias[obase + h] : 0.f;
#pragma unroll
    for (int off = 1; off < 64; off <<= 1) p += __shfl_xor(p, off, 64);

    __shared__ float red[8];
    const int wid  = h >> 6;
    const int lane = h & 63;
    if (lane == 0) red[wid] = p;
    __syncthreads();
    if (h == 0) {
        float s = 0.f;
#pragma unroll
        for (int w = 0; w < 8; ++w) s += red[w];
        cpart[part * BATCH + b] = s;
    }
}

// -----------------------------------------------------------------------------
// Kernel 2: energies[b,l] = enc[b,l,:] . v[b,:] + c[b]   (unchanged from R7)
// -----------------------------------------------------------------------------
__global__ __launch_bounds__(256) void energy_kernel(
    const float* __restrict__ enc, const float* __restrict__ vpart,
    const float* __restrict__ cpart, float* __restrict__ energies)
{
    const int wave = threadIdx.x >> 6;
    const int lane = threadIdx.x & 63;
    const int sub  = lane >> 4;
    const int sl   = lane & 15;

    const int b      = blockIdx.x >> 5;
    const int l_base = (blockIdx.x & 31) * 128 + wave * 32;

    const f32x4* vp0 = (const f32x4*)(vpart + (0 * BATCH + b) * HDIM);
    const f32x4* vp1 = (const f32x4*)(vpart + (1 * BATCH + b) * HDIM);
    const f32x4* vp2 = (const f32x4*)(vpart + (2 * BATCH + b) * HDIM);
    const f32x4* vp3 = (const f32x4*)(vpart + (3 * BATCH + b) * HDIM);
    f32x4 vv[8];
#pragma unroll
    for (int k = 0; k < 8; ++k) {
        const int ch = sl + 16 * k;
        vv[k] = vp0[ch] + vp1[ch] + vp2[ch] + vp3[ch];
    }
    const float cb = cpart[b] + cpart[BATCH + b] + cpart[2 * BATCH + b]
                   + cpart[3 * BATCH + b];

    const long rbase = (long)b * LSEQ + l_base;
    const bool resident_half = (b < BATCH / 2);

#pragma unroll 2
    for (int batch = 0; batch < 8; ++batch) {
        const long r = rbase + batch * 4 + sub;
        const f32x4* ep = (const f32x4*)(enc + r * HDIM) + sl;

        f32x4 e[8];
        if (resident_half) {
#pragma unroll
            for (int k = 0; k < 8; ++k)
                e[k] = ep[16 * k];                       // allocate in L3
        } else {
#pragma unroll
            for (int k = 0; k < 8; ++k)
                e[k] = __builtin_nontemporal_load(ep + 16 * k);  // stream
        }

        float d = 0.f;
#pragma unroll
        for (int k = 0; k < 8; ++k) {
            d += e[k].x * vv[k].x + e[k].y * vv[k].y
               + e[k].z * vv[k].z + e[k].w * vv[k].w;
        }

        d += __shfl_xor(d, 1, 64);
        d += __shfl_xor(d, 2, 64);
        d += __shfl_xor(d, 4, 64);
        d += __shfl_xor(d, 8, 64);

        if (sl == 0) energies[r] = d + cb;
    }
}

// -----------------------------------------------------------------------------
// Kernel 3: softmax, 8 blocks per row (256 blocks x 256 threads).
// Every block redundantly computes the full-row max/sum (identical reduction
// order -> bitwise-identical results) and writes the full row; concurrent
// identical-byte writes are deterministic. Removes the 32-block (12.5% CU)
// underutilization of the old version. Traffic is L2/L3-resident.
// -----------------------------------------------------------------------------
__global__ __launch_bounds__(256) void softmax_kernel(float* __restrict__ out)
{
    const int b = blockIdx.x >> 3;          // 8 blocks per batch row
    const int t = threadIdx.x;
    const int wid  = t >> 6;
    const int lane = t & 63;

    float4* o4 = (float4*)(out + (long)b * LSEQ);   // 1024 float4 per row

    float4 vals[4];
    float m = -3.402823466e+38f;
#pragma unroll
    for (int i = 0; i < 4; ++i) {
        vals[i] = o4[i * 256 + t];                  // coalesced
        m = fmaxf(m, fmaxf(fmaxf(vals[i].x, vals[i].y),
                           fmaxf(vals[i].z, vals[i].w)));
    }

    __shared__ float smax[4];
#pragma unroll
    for (int off = 1; off < 64; off <<= 1) m = fmaxf(m, __shfl_xor(m, off, 64));
    if (lane == 0) smax[wid] = m;
    __syncthreads();
    m = fmaxf(fmaxf(smax[0], smax[1]), fmaxf(smax[2], smax[3]));

    float s = 0.f;
#pragma unroll
    for (int i = 0; i < 4; ++i) {
        vals[i].x = __expf(vals[i].x - m);
        vals[i].y = __expf(vals[i].y - m);
        vals[i].z = __expf(vals[i].z - m);
        vals[i].w = __expf(vals[i].w - m);
        s += vals[i].x + vals[i].y + vals[i].z + vals[i].w;
    }
    __shared__ float ssum[4];
#pragma unroll
    for (int off = 1; off < 64; off <<= 1) s += __shfl_xor(s, off, 64);
    if (lane == 0) ssum[wid] = s;
    __syncthreads();
    s = ssum[0] + ssum[1] + ssum[2] + ssum[3];

    const float inv = 1.0f / s;
#pragma unroll
    for (int i = 0; i < 4; ++i) {
        float4 w = vals[i];
        w.x *= inv; w.y *= inv; w.z *= inv; w.w *= inv;
        o4[i * 256 + t] = w;                        // identical bytes from all 8 blocks
    }
}

// -----------------------------------------------------------------------------
extern "C" void kernel_launch(void* const* d_in, const int* in_sizes, int n_in,
                              void* d_out, int out_size, void* d_ws, size_t ws_size,
                              hipStream_t stream)
{
    const float* hidden = (const float*)d_in[0];   // (2,2,B,H)
    const float* enc    = (const float*)d_in[1];   // (B,L,H)
    const float* W      = (const float*)d_in[2];   // (H,H)
    const float* bias   = (const float*)d_in[3];   // (H,)

    float* ws    = (float*)d_ws;
    float* vpart = ws;                               // PARTS*B*H floats
    float* cpart = ws + PARTS * BATCH * HDIM;        // PARTS*B floats

    float* out = (float*)d_out;                      // B*L floats

    proj_kernel<<<dim3(BATCH, PARTS), 512, 0, stream>>>(hidden, W, bias, vpart, cpart);
    energy_kernel<<<(BATCH * LSEQ) / 128, 256, 0, stream>>>(enc, vpart, cpart, out);
    softmax_kernel<<<BATCH * 8, 256, 0, stream>>>(out);
}

// Round 9
// 55.435 us; speedup vs baseline: 1.0444x; 1.0444x over previous
//
#include <hip/hip_runtime.h>

#define BATCH 32
#define LSEQ 4096
#define HDIM 512
#define PARTS 4

typedef float f32x4 __attribute__((ext_vector_type(4)));

// -----------------------------------------------------------------------------
// Kernel 1: partial projection. grid (BATCH, PARTS), block 512.  (unchanged)
// -----------------------------------------------------------------------------
__global__ __launch_bounds__(512) void proj_kernel(
    const float* __restrict__ hidden, const float* __restrict__ W,
    const float* __restrict__ bias, float* __restrict__ vpart,
    float* __restrict__ cpart)
{
    const int b    = blockIdx.x;
    const int part = blockIdx.y;
    const int h    = threadIdx.x;
    const int OS   = HDIM / PARTS;          // 128
    const int obase = part * OS;

    __shared__ float s_hl[HDIM / PARTS];
    if (h < OS) s_hl[h] = hidden[(BATCH + b) * HDIM + obase + h];
    __syncthreads();

    float acc = 0.f;
#pragma unroll 16
    for (int o = 0; o < OS; ++o) {
        acc += s_hl[o] * W[(obase + o) * HDIM + h];
    }
    vpart[(part * BATCH + b) * HDIM + h] = acc;

    float p = (h < OS) ? s_hl[h] * bias[obase + h] : 0.f;
#pragma unroll
    for (int off = 1; off < 64; off <<= 1) p += __shfl_xor(p, off, 64);

    __shared__ float red[8];
    const int wid  = h >> 6;
    const int lane = h & 63;
    if (lane == 0) red[wid] = p;
    __syncthreads();
    if (h == 0) {
        float s = 0.f;
#pragma unroll
        for (int w = 0; w < 8; ++w) s += red[w];
        cpart[part * BATCH + b] = s;
    }
}

// -----------------------------------------------------------------------------
// Kernel 2: energies[b,l] = enc[b,l,:] . v[b,:] + c[b]
// Explicit 2-deep software pipeline: iteration i+1's 8 loads are issued
// BEFORE iteration i's FMA block (16 loads in flight per lane), and the
// dot uses 4 independent accumulators (dependency chain 32 -> 8).
// 16 lanes per row; 32 rows/wave; block 256 = 128 rows; grid 1024.
// -----------------------------------------------------------------------------
__global__ __launch_bounds__(256) void energy_kernel(
    const float* __restrict__ enc, const float* __restrict__ vpart,
    const float* __restrict__ cpart, float* __restrict__ energies)
{
    const int wave = threadIdx.x >> 6;
    const int lane = threadIdx.x & 63;
    const int sub  = lane >> 4;
    const int sl   = lane & 15;

    const int b      = blockIdx.x >> 5;
    const int l_base = (blockIdx.x & 31) * 128 + wave * 32;

    const f32x4* vp0 = (const f32x4*)(vpart + (0 * BATCH + b) * HDIM);
    const f32x4* vp1 = (const f32x4*)(vpart + (1 * BATCH + b) * HDIM);
    const f32x4* vp2 = (const f32x4*)(vpart + (2 * BATCH + b) * HDIM);
    const f32x4* vp3 = (const f32x4*)(vpart + (3 * BATCH + b) * HDIM);
    f32x4 vv[8];
#pragma unroll
    for (int k = 0; k < 8; ++k) {
        const int ch = sl + 16 * k;
        vv[k] = vp0[ch] + vp1[ch] + vp2[ch] + vp3[ch];
    }
    const float cb = cpart[b] + cpart[BATCH + b] + cpart[2 * BATCH + b]
                   + cpart[3 * BATCH + b];

    const long rbase = (long)b * LSEQ + l_base;
    const bool resident_half = (b < BATCH / 2);

    const f32x4* ep0 = (const f32x4*)(enc + (rbase + sub) * HDIM) + sl;

    f32x4 eA[8], eB[8];
    // prologue: load batch 0
    if (resident_half) {
#pragma unroll
        for (int k = 0; k < 8; ++k) eA[k] = ep0[16 * k];
    } else {
#pragma unroll
        for (int k = 0; k < 8; ++k) eA[k] = __builtin_nontemporal_load(ep0 + 16 * k);
    }

#pragma unroll
    for (int batch = 0; batch < 8; ++batch) {
        // issue next batch's loads first (hide under this batch's FMAs)
        if (batch < 7) {
            const f32x4* epn = ep0 + (batch + 1) * 4 * (HDIM / 4) * 1;  // +4 rows
            const f32x4* ep  = (const f32x4*)(enc + (rbase + (batch + 1) * 4 + sub) * HDIM) + sl;
            (void)epn;
            if (resident_half) {
#pragma unroll
                for (int k = 0; k < 8; ++k) eB[k] = ep[16 * k];
            } else {
#pragma unroll
                for (int k = 0; k < 8; ++k) eB[k] = __builtin_nontemporal_load(ep + 16 * k);
            }
        }

        // 4 independent accumulator chains
        float d0 = eA[0].x * vv[0].x + eA[0].y * vv[0].y
                 + eA[0].z * vv[0].z + eA[0].w * vv[0].w;
        float d1 = eA[1].x * vv[1].x + eA[1].y * vv[1].y
                 + eA[1].z * vv[1].z + eA[1].w * vv[1].w;
        float d2 = eA[2].x * vv[2].x + eA[2].y * vv[2].y
                 + eA[2].z * vv[2].z + eA[2].w * vv[2].w;
        float d3 = eA[3].x * vv[3].x + eA[3].y * vv[3].y
                 + eA[3].z * vv[3].z + eA[3].w * vv[3].w;
        d0 += eA[4].x * vv[4].x + eA[4].y * vv[4].y
            + eA[4].z * vv[4].z + eA[4].w * vv[4].w;
        d1 += eA[5].x * vv[5].x + eA[5].y * vv[5].y
            + eA[5].z * vv[5].z + eA[5].w * vv[5].w;
        d2 += eA[6].x * vv[6].x + eA[6].y * vv[6].y
            + eA[6].z * vv[6].z + eA[6].w * vv[6].w;
        d3 += eA[7].x * vv[7].x + eA[7].y * vv[7].y
            + eA[7].z * vv[7].z + eA[7].w * vv[7].w;
        float d = (d0 + d1) + (d2 + d3);

        d += __shfl_xor(d, 1, 64);
        d += __shfl_xor(d, 2, 64);
        d += __shfl_xor(d, 4, 64);
        d += __shfl_xor(d, 8, 64);

        if (sl == 0) energies[rbase + batch * 4 + sub] = d + cb;

        // rotate pipeline registers (renamed away by unrolled loop)
#pragma unroll
        for (int k = 0; k < 8; ++k) eA[k] = eB[k];
    }
}

// -----------------------------------------------------------------------------
// Kernel 3: softmax over L per batch row, in place. (R7 version: 32 x 1024)
// -----------------------------------------------------------------------------
__global__ __launch_bounds__(1024) void softmax_kernel(float* __restrict__ out)
{
    const int b = blockIdx.x;
    const int t = threadIdx.x;
    const int wid  = t >> 6;
    const int lane = t & 63;

    float4* o4 = (float4*)(out + (long)b * LSEQ);

    float4 v0 = o4[t];
    float m = fmaxf(fmaxf(v0.x, v0.y), fmaxf(v0.z, v0.w));

    __shared__ float smax[16];
#pragma unroll
    for (int off = 1; off < 64; off <<= 1) m = fmaxf(m, __shfl_xor(m, off, 64));
    if (lane == 0) smax[wid] = m;
    __syncthreads();
#pragma unroll
    for (int w = 0; w < 16; ++w) m = fmaxf(m, smax[w]);

    v0.x = __expf(v0.x - m); v0.y = __expf(v0.y - m);
    v0.z = __expf(v0.z - m); v0.w = __expf(v0.w - m);

    float s = v0.x + v0.y + v0.z + v0.w;
    __shared__ float ssum[16];
#pragma unroll
    for (int off = 1; off < 64; off <<= 1) s += __shfl_xor(s, off, 64);
    if (lane == 0) ssum[wid] = s;
    __syncthreads();
    s = 0.f;
#pragma unroll
    for (int w = 0; w < 16; ++w) s += ssum[w];

    const float inv = 1.0f / s;
    v0.x *= inv; v0.y *= inv; v0.z *= inv; v0.w *= inv;
    o4[t] = v0;
}

// -----------------------------------------------------------------------------
extern "C" void kernel_launch(void* const* d_in, const int* in_sizes, int n_in,
                              void* d_out, int out_size, void* d_ws, size_t ws_size,
                              hipStream_t stream)
{
    const float* hidden = (const float*)d_in[0];   // (2,2,B,H)
    const float* enc    = (const float*)d_in[1];   // (B,L,H)
    const float* W      = (const float*)d_in[2];   // (H,H)
    const float* bias   = (const float*)d_in[3];   // (H,)

    float* ws    = (float*)d_ws;
    float* vpart = ws;                               // PARTS*B*H floats
    float* cpart = ws + PARTS * BATCH * HDIM;        // PARTS*B floats

    float* out = (float*)d_out;                      // B*L floats

    proj_kernel<<<dim3(BATCH, PARTS), 512, 0, stream>>>(hidden, W, bias, vpart, cpart);
    energy_kernel<<<(BATCH * LSEQ) / 128, 256, 0, stream>>>(enc, vpart, cpart, out);
    softmax_kernel<<<BATCH, 1024, 0, stream>>>(out);
}

// Round 10
// 53.847 us; speedup vs baseline: 1.0752x; 1.0295x over previous
//
#include <hip/hip_runtime.h>

#define BATCH 32
#define LSEQ 4096
#define HDIM 512
#define PARTS 4

typedef float f32x4 __attribute__((ext_vector_type(4)));

// -----------------------------------------------------------------------------
// Kernel 1: partial projection. grid (BATCH, PARTS), block 512.
// vpart[p][b][h] = sum_{o in slice p} h_last[b][o] * W[o][h]
// NOTE: the reference's "+ b" bias adds a per-row constant to the energies,
// which softmax cancels exactly -> bias is dropped entirely.
// -----------------------------------------------------------------------------
__global__ __launch_bounds__(512) void proj_kernel(
    const float* __restrict__ hidden, const float* __restrict__ W,
    float* __restrict__ vpart)
{
    const int b    = blockIdx.x;
    const int part = blockIdx.y;
    const int h    = threadIdx.x;
    const int OS   = HDIM / PARTS;          // 128
    const int obase = part * OS;

    __shared__ float s_hl[HDIM / PARTS];
    if (h < OS) s_hl[h] = hidden[(BATCH + b) * HDIM + obase + h];
    __syncthreads();

    float acc = 0.f;
#pragma unroll 16
    for (int o = 0; o < OS; ++o) {
        acc += s_hl[o] * W[(obase + o) * HDIM + h];
    }
    vpart[(part * BATCH + b) * HDIM + h] = acc;
}

// -----------------------------------------------------------------------------
// Kernel 2: energies[b,l] = enc[b,l,:] . v[b,:]
// 16 lanes per row; 16 rows per wave; 64 rows per block; grid 2048
// (8 blocks/CU candidate). __launch_bounds__(256,5) caps VGPR at ~102 ->
// 20 waves/CU resident for deeper latency hiding on the HBM stream.
// -----------------------------------------------------------------------------
__global__ __launch_bounds__(256, 5) void energy_kernel(
    const float* __restrict__ enc, const float* __restrict__ vpart,
    float* __restrict__ energies)
{
    const int wave = threadIdx.x >> 6;
    const int lane = threadIdx.x & 63;
    const int sub  = lane >> 4;
    const int sl   = lane & 15;

    const int b      = blockIdx.x >> 6;            // 64 blocks per batch row
    const int l_base = (blockIdx.x & 63) * 64 + wave * 16;

    // hoist v = sum of 4 partials (L2-resident, 256KB total)
    const f32x4* vp0 = (const f32x4*)(vpart + (0 * BATCH + b) * HDIM);
    const f32x4* vp1 = (const f32x4*)(vpart + (1 * BATCH + b) * HDIM);
    const f32x4* vp2 = (const f32x4*)(vpart + (2 * BATCH + b) * HDIM);
    const f32x4* vp3 = (const f32x4*)(vpart + (3 * BATCH + b) * HDIM);
    f32x4 vv[8];
#pragma unroll
    for (int k = 0; k < 8; ++k) {
        const int ch = sl + 16 * k;
        vv[k] = vp0[ch] + vp1[ch] + vp2[ch] + vp3[ch];
    }

    const long rbase = (long)b * LSEQ + l_base;

#pragma unroll
    for (int batch = 0; batch < 4; ++batch) {
        const long r = rbase + batch * 4 + sub;
        const f32x4* ep = (const f32x4*)(enc + r * HDIM) + sl;

        f32x4 e[8];
#pragma unroll
        for (int k = 0; k < 8; ++k)
            e[k] = ep[16 * k];

        float d0 = e[0].x * vv[0].x + e[0].y * vv[0].y
                 + e[0].z * vv[0].z + e[0].w * vv[0].w;
        float d1 = e[1].x * vv[1].x + e[1].y * vv[1].y
                 + e[1].z * vv[1].z + e[1].w * vv[1].w;
        float d2 = e[2].x * vv[2].x + e[2].y * vv[2].y
                 + e[2].z * vv[2].z + e[2].w * vv[2].w;
        float d3 = e[3].x * vv[3].x + e[3].y * vv[3].y
                 + e[3].z * vv[3].z + e[3].w * vv[3].w;
        d0 += e[4].x * vv[4].x + e[4].y * vv[4].y
            + e[4].z * vv[4].z + e[4].w * vv[4].w;
        d1 += e[5].x * vv[5].x + e[5].y * vv[5].y
            + e[5].z * vv[5].z + e[5].w * vv[5].w;
        d2 += e[6].x * vv[6].x + e[6].y * vv[6].y
            + e[6].z * vv[6].z + e[6].w * vv[6].w;
        d3 += e[7].x * vv[7].x + e[7].y * vv[7].y
            + e[7].z * vv[7].z + e[7].w * vv[7].w;
        float d = (d0 + d1) + (d2 + d3);

        d += __shfl_xor(d, 1, 64);
        d += __shfl_xor(d, 2, 64);
        d += __shfl_xor(d, 4, 64);
        d += __shfl_xor(d, 8, 64);

        if (sl == 0) energies[r] = d;
    }
}

// -----------------------------------------------------------------------------
// Kernel 3: softmax over L per batch row, in place. 32 blocks x 1024 threads.
// -----------------------------------------------------------------------------
__global__ __launch_bounds__(1024) void softmax_kernel(float* __restrict__ out)
{
    const int b = blockIdx.x;
    const int t = threadIdx.x;
    const int wid  = t >> 6;
    const int lane = t & 63;

    float4* o4 = (float4*)(out + (long)b * LSEQ);

    float4 v0 = o4[t];
    float m = fmaxf(fmaxf(v0.x, v0.y), fmaxf(v0.z, v0.w));

    __shared__ float smax[16];
#pragma unroll
    for (int off = 1; off < 64; off <<= 1) m = fmaxf(m, __shfl_xor(m, off, 64));
    if (lane == 0) smax[wid] = m;
    __syncthreads();
#pragma unroll
    for (int w = 0; w < 16; ++w) m = fmaxf(m, smax[w]);

    v0.x = __expf(v0.x - m); v0.y = __expf(v0.y - m);
    v0.z = __expf(v0.z - m); v0.w = __expf(v0.w - m);

    float s = v0.x + v0.y + v0.z + v0.w;
    __shared__ float ssum[16];
#pragma unroll
    for (int off = 1; off < 64; off <<= 1) s += __shfl_xor(s, off, 64);
    if (lane == 0) ssum[wid] = s;
    __syncthreads();
    s = 0.f;
#pragma unroll
    for (int w = 0; w < 16; ++w) s += ssum[w];

    const float inv = 1.0f / s;
    v0.x *= inv; v0.y *= inv; v0.z *= inv; v0.w *= inv;
    o4[t] = v0;
}

// -----------------------------------------------------------------------------
extern "C" void kernel_launch(void* const* d_in, const int* in_sizes, int n_in,
                              void* d_out, int out_size, void* d_ws, size_t ws_size,
                              hipStream_t stream)
{
    const float* hidden = (const float*)d_in[0];   // (2,2,B,H)
    const float* enc    = (const float*)d_in[1];   // (B,L,H)
    const float* W      = (const float*)d_in[2];   // (H,H)

    float* ws    = (float*)d_ws;
    float* vpart = ws;                               // PARTS*B*H floats

    float* out = (float*)d_out;                      // B*L floats

    proj_kernel<<<dim3(BATCH, PARTS), 512, 0, stream>>>(hidden, W, vpart);
    energy_kernel<<<(BATCH * LSEQ) / 64, 256, 0, stream>>>(enc, vpart, out);
    softmax_kernel<<<BATCH, 1024, 0, stream>>>(out);
}